// Round 10
// baseline (391.649 us; speedup 1.0000x reference)
//
#include <hip/hip_runtime.h>
#include <math.h>

// ---------------------------------------------------------------------------
// GCN 2-layer forward on MI355X.
// Round 9 (verbatim resubmit; rounds 4-8 benches never ran — infra failures):
//  * agg: XCD-pinned feature slicing. Each block gathers one 16-float
//    (64 B = 1 cache line) slice, slice = blockIdx.x % NSLICE matching the
//    round-robin block->XCD dispatch, so each XCD's L2 working set is
//    50000 lines x 64 B = 3.2 MB < 4 MB private L2. Gathers become L2 hits.
//  * gemm: 32-row tiles (1563 blocks, 6 blocks/CU) for 2x TLP.
// CSR build unchanged: one packed 64-bit atomic per edge
//   bits [40:63] = incoming-edge count, bits [0:39] = fixed-point wsum (2^-24)
// atomic return value -> edge rank -> atomic-free CSR fill of int2{src,norm}.
// ---------------------------------------------------------------------------

#define WFIX_SCALE 16777216.0f  // 2^24
#define WFIX_MASK  0xFFFFFFFFFFULL

// --- dtype detect: flag=1 if edge_index is int64 (all sampled high words 0) ---
__global__ __launch_bounds__(256) void k_detect(const int* __restrict__ ei,
                                                int* __restrict__ flagp, int E) {
  __shared__ int sm[256];
  int t = threadIdx.x;
  int v = 0;
#pragma unroll
  for (int j = 0; j < 8; ++j) {
    int e = t * 8 + j;           // e < 2048, safely inside both layouts
    if (2 * e + 1 < 2 * E) v |= ei[2 * e + 1];
  }
  sm[t] = v;
  __syncthreads();
  for (int off = 128; off > 0; off >>= 1) {
    if (t < off) sm[t] |= sm[t + off];
    __syncthreads();
  }
  if (t == 0) flagp[0] = (sm[0] == 0) ? 1 : 0;
}

__global__ __launch_bounds__(256) void k_init(unsigned long long* __restrict__ packed,
                                              int N) {
  int i = blockIdx.x * 256 + threadIdx.x;
  if (i < N) packed[i] = 0ULL;
}

// one packed 64-bit atomic per edge; returned old value -> rank within dst row
__global__ __launch_bounds__(256) void k_hist2(const int* __restrict__ ei,
                                               const float* __restrict__ ew,
                                               unsigned long long* __restrict__ packed,
                                               unsigned short* __restrict__ rank,
                                               int E, const int* __restrict__ flagp) {
  int e = blockIdx.x * 256 + threadIdx.x;
  if (e >= E) return;
  int is64 = flagp[0];
  int d = is64 ? ei[2 * E + 2 * e] : ei[E + e];
  unsigned long long wfix = (unsigned long long)(ew[e] * WFIX_SCALE + 0.5f);
  unsigned long long old = atomicAdd(&packed[d], wfix | (1ULL << 40));
  rank[e] = (unsigned short)(old >> 40);
}

// unpack: dinv = rsqrt(1 + wsum), cnt; and block-sum cnt for the scan
__global__ __launch_bounds__(256) void k_dinv_scan1(
    const unsigned long long* __restrict__ packed, float* __restrict__ dinv,
    int* __restrict__ cnt, int* __restrict__ bsum, int N) {
  __shared__ int sm[256];
  int t = threadIdx.x;
  int i = blockIdx.x * 256 + t;
  int c = 0;
  if (i < N) {
    unsigned long long p = packed[i];
    c = (int)(p >> 40);
    float deg = 1.0f + (float)(p & WFIX_MASK) * (1.0f / WFIX_SCALE);
    dinv[i] = rsqrtf(deg);
    cnt[i] = c;
  }
  sm[t] = c;
  __syncthreads();
  for (int off = 128; off > 0; off >>= 1) {
    if (t < off) sm[t] += sm[t + off];
    __syncthreads();
  }
  if (t == 0) bsum[blockIdx.x] = sm[0];
}

__global__ __launch_bounds__(256) void k_scan2(int* __restrict__ bsum,
                                               int* __restrict__ row_start,
                                               int NB, int N, int E) {
  __shared__ int sm[256];
  int t = threadIdx.x;
  int v = (t < NB) ? bsum[t] : 0;
  sm[t] = v;
  __syncthreads();
  for (int off = 1; off < 256; off <<= 1) {
    int add = (t >= off) ? sm[t - off] : 0;
    __syncthreads();
    sm[t] += add;
    __syncthreads();
  }
  if (t < NB) bsum[t] = sm[t] - v;  // exclusive block offsets
  if (t == 0) row_start[N] = E;
}

__global__ __launch_bounds__(256) void k_scan3(const int* __restrict__ cnt,
                                               const int* __restrict__ bsum,
                                               int* __restrict__ row_start, int N) {
  __shared__ int sm[256];
  int t = threadIdx.x;
  int i = blockIdx.x * 256 + t;
  int v = (i < N) ? cnt[i] : 0;
  sm[t] = v;
  __syncthreads();
  for (int off = 1; off < 256; off <<= 1) {
    int add = (t >= off) ? sm[t - off] : 0;
    __syncthreads();
    sm[t] += add;
    __syncthreads();
  }
  if (i < N) row_start[i] = sm[t] - v + bsum[blockIdx.x];
}

// CSR fill, atomic-free: pos = row_start[dst] + rank[e]; one packed int2 store
__global__ __launch_bounds__(256) void k_fill2(const int* __restrict__ ei,
                                               const float* __restrict__ ew,
                                               const float* __restrict__ dinv,
                                               const int* __restrict__ row_start,
                                               const unsigned short* __restrict__ rank,
                                               int2* __restrict__ csr, int E,
                                               const int* __restrict__ flagp) {
  int e = blockIdx.x * 256 + threadIdx.x;
  if (e >= E) return;
  int is64 = flagp[0];
  int s, d;
  if (is64) { s = ei[2 * e]; d = ei[2 * E + 2 * e]; }
  else      { s = ei[e];     d = ei[E + e]; }
  float nw = dinv[s] * ew[e] * dinv[d];
  int pos = row_start[d] + (int)rank[e];
  csr[pos] = make_int2(s, __float_as_int(nw));
}

// --- fp32 register-tiled GEMM: Y[M,NC] = X[M,128] @ W[128,NC] ---
// 32 rows per block for TLP (6 blocks/CU at 1563 blocks).
template <int NC>
__global__ __launch_bounds__(256) void gemm_kernel(const float* __restrict__ X,
                                                   const float* __restrict__ W,
                                                   float* __restrict__ Y, int M) {
  constexpr int K = 128;
  constexpr int CG = NC / 4;    // col groups: 32 (NC=128) or 16 (NC=64)
  constexpr int RS = 256 / CG;  // row subs: 8 or 16
  constexpr int RI = 32 / RS;   // rows per thread: 4 or 2
  int t = threadIdx.x;
  int cg = t % CG;
  int rs = t / CG;
  int rbase = blockIdx.x * 32;

  float4 acc[RI];
#pragma unroll
  for (int i = 0; i < RI; ++i) acc[i] = make_float4(0.f, 0.f, 0.f, 0.f);

  int rows[RI];
#pragma unroll
  for (int i = 0; i < RI; ++i) {
    int r = rbase + rs + RS * i;
    rows[i] = (r < M) ? r : (M - 1);  // clamp loads, guard stores
  }

  for (int k0 = 0; k0 < K; k0 += 4) {
    float4 w[4];
#pragma unroll
    for (int j = 0; j < 4; ++j)
      w[j] = *(const float4*)&W[(k0 + j) * NC + 4 * cg];
#pragma unroll
    for (int i = 0; i < RI; ++i) {
      float4 xq = *(const float4*)&X[(size_t)rows[i] * K + k0];
      acc[i].x += xq.x * w[0].x + xq.y * w[1].x + xq.z * w[2].x + xq.w * w[3].x;
      acc[i].y += xq.x * w[0].y + xq.y * w[1].y + xq.z * w[2].y + xq.w * w[3].y;
      acc[i].z += xq.x * w[0].z + xq.y * w[1].z + xq.z * w[2].z + xq.w * w[3].z;
      acc[i].w += xq.x * w[0].w + xq.y * w[1].w + xq.z * w[2].w + xq.w * w[3].w;
    }
  }

#pragma unroll
  for (int i = 0; i < RI; ++i) {
    int r = rbase + rs + RS * i;
    if (r < M) *(float4*)&Y[(size_t)r * NC + 4 * cg] = acc[i];
  }
}

// --- XCD-pinned sliced aggregation, fused self-loop + bias (+ReLU) ---
// Each block handles ONE 16-float slice (= one 64B cache line per node) for
// 64 nodes. slice = blockIdx.x % NSLICE matches round-robin block->XCD
// dispatch -> per-XCD L2 working set = N*64B = 3.2 MB (fits 4 MB L2).
// 4 lanes per node; lane reads float4 at fbase = slice*16 + lane*4.
template <int NC, int NSLICE, bool RELU>
__global__ __launch_bounds__(256) void agg_sliced(const float* __restrict__ H,
                                                  const int* __restrict__ row_start,
                                                  const int2* __restrict__ csr,
                                                  const float* __restrict__ dinv,
                                                  const float* __restrict__ bias,
                                                  float* __restrict__ OUT, int N) {
  int b = blockIdx.x;
  int s = b % NSLICE;
  int chunk = b / NSLICE;
  int t = threadIdx.x;
  int lane = t & 3;
  int n = chunk * 64 + (t >> 2);
  if (n >= N) return;

  int fbase = s * 16 + lane * 4;
  const float* Hf = H + fbase;

  int j0 = row_start[n];
  int j1 = row_start[n + 1];
  float4 acc = make_float4(0.f, 0.f, 0.f, 0.f);

  int j = j0;
  for (; j + 4 <= j1; j += 4) {
    int2 e0 = csr[j];
    int2 e1 = csr[j + 1];
    int2 e2 = csr[j + 2];
    int2 e3 = csr[j + 3];
    float4 h0 = *(const float4*)&Hf[(size_t)e0.x * NC];
    float4 h1 = *(const float4*)&Hf[(size_t)e1.x * NC];
    float4 h2 = *(const float4*)&Hf[(size_t)e2.x * NC];
    float4 h3 = *(const float4*)&Hf[(size_t)e3.x * NC];
    float w0 = __int_as_float(e0.y);
    float w1 = __int_as_float(e1.y);
    float w2 = __int_as_float(e2.y);
    float w3 = __int_as_float(e3.y);
    acc.x += w0 * h0.x + w1 * h1.x + w2 * h2.x + w3 * h3.x;
    acc.y += w0 * h0.y + w1 * h1.y + w2 * h2.y + w3 * h3.y;
    acc.z += w0 * h0.z + w1 * h1.z + w2 * h2.z + w3 * h3.z;
    acc.w += w0 * h0.w + w1 * h1.w + w2 * h2.w + w3 * h3.w;
  }
  for (; j < j1; ++j) {
    int2 sn = csr[j];
    float w = __int_as_float(sn.y);
    float4 h = *(const float4*)&Hf[(size_t)sn.x * NC];
    acc.x += w * h.x; acc.y += w * h.y; acc.z += w * h.z; acc.w += w * h.w;
  }

  float di = dinv[n];
  float sw = di * di;
  float4 hs = *(const float4*)&Hf[(size_t)n * NC];
  float4 bb = *(const float4*)&bias[fbase];
  float4 o;
  o.x = acc.x + sw * hs.x + bb.x;
  o.y = acc.y + sw * hs.y + bb.y;
  o.z = acc.z + sw * hs.z + bb.z;
  o.w = acc.w + sw * hs.w + bb.w;
  if (RELU) {
    o.x = fmaxf(o.x, 0.f); o.y = fmaxf(o.y, 0.f);
    o.z = fmaxf(o.z, 0.f); o.w = fmaxf(o.w, 0.f);
  }
  *(float4*)&OUT[(size_t)n * NC + fbase] = o;
}

extern "C" void kernel_launch(void* const* d_in, const int* in_sizes, int n_in,
                              void* d_out, int out_size, void* d_ws, size_t ws_size,
                              hipStream_t stream) {
  const float* x  = (const float*)d_in[0];
  const int*   ei = (const int*)d_in[1];
  const float* ew = (const float*)d_in[2];
  const float* W1 = (const float*)d_in[3];
  const float* b1 = (const float*)d_in[4];
  const float* W2 = (const float*)d_in[5];
  const float* b2 = (const float*)d_in[6];
  float* out = (float*)d_out;

  const int IN_D = 128, HID = 128, OUT_D = 64;
  const int N = in_sizes[0] / IN_D;   // 50000
  const int E = in_sizes[2];          // 800000

  char* ws = (char*)d_ws;
  size_t off = 0;
  auto take = [&](size_t bytes) -> void* {
    void* p = ws + off;
    off += (bytes + 255) & ~(size_t)255;
    return p;
  };
  unsigned long long* packed = (unsigned long long*)take((size_t)N * 8);
  float* dinv      = (float*)take((size_t)N * 4);
  int*   cnt       = (int*)take((size_t)N * 4);
  int*   row_start = (int*)take((size_t)(N + 1) * 4);
  int*   bsum      = (int*)take(256 * 4);
  int*   flag      = (int*)take(256);
  unsigned short* rank = (unsigned short*)take((size_t)E * 2);
  int2*  csr       = (int2*)take((size_t)E * 8);
  float* h1        = (float*)take((size_t)N * HID * 4);
  float* h2        = (float*)take((size_t)N * HID * 4);
  float* h3        = (float*)take((size_t)N * OUT_D * 4);

  int nb_n = (N + 255) / 256;  // 196
  int nb_e = (E + 255) / 256;  // 3125
  int nb_g = (N + 31) / 32;    // 1563
  int nchunk = (N + 63) / 64;  // 782

  hipLaunchKernelGGL(k_detect, dim3(1), dim3(256), 0, stream, ei, flag, E);
  hipLaunchKernelGGL(k_init, dim3(nb_n), dim3(256), 0, stream, packed, N);
  hipLaunchKernelGGL(k_hist2, dim3(nb_e), dim3(256), 0, stream, ei, ew, packed, rank, E, flag);
  hipLaunchKernelGGL(k_dinv_scan1, dim3(nb_n), dim3(256), 0, stream, packed, dinv, cnt, bsum, N);
  hipLaunchKernelGGL(k_scan2, dim3(1), dim3(256), 0, stream, bsum, row_start, nb_n, N, E);
  hipLaunchKernelGGL(k_scan3, dim3(nb_n), dim3(256), 0, stream, cnt, bsum, row_start, N);
  hipLaunchKernelGGL(k_fill2, dim3(nb_e), dim3(256), 0, stream, ei, ew, dinv, row_start,
                     rank, csr, E, flag);
  hipLaunchKernelGGL((gemm_kernel<128>), dim3(nb_g), dim3(256), 0, stream, x, W1, h1, N);
  hipLaunchKernelGGL((agg_sliced<128, 8, true>), dim3(8 * nchunk), dim3(256), 0, stream,
                     h1, row_start, csr, dinv, b1, h2, N);
  hipLaunchKernelGGL((gemm_kernel<64>), dim3(nb_g), dim3(256), 0, stream, h2, W2, h3, N);
  hipLaunchKernelGGL((agg_sliced<64, 4, false>), dim3(4 * nchunk), dim3(256), 0, stream,
                     h3, row_start, csr, dinv, b2, out, N);
}

// Round 14
// 296.582 us; speedup vs baseline: 1.3205x; 1.3205x over previous
//
#include <hip/hip_runtime.h>
#include <hip/hip_fp16.h>
#include <math.h>

// ---------------------------------------------------------------------------
// GCN 2-layer forward on MI355X.
// Round 13 resubmit (rounds 11-12 benches never ran — GPU acquisition
// timeouts):
//  * SLICING REVERTED (falsified: FETCH 188->298 MB, 60->95 us). agg back to
//    round-4 unsliced 4-way-unrolled gather (measured 60 us), but now the
//    gathered features (GEMM outputs h1, h3) are stored fp16: halves the
//    per-XCD compulsory L2-fill floor (8 XCD x 25.6 MB -> x 12.8 MB) and the
//    gather bandwidth. Accumulation stays fp32.
//  * gemm: 32-row tiles kept (6 blocks/CU TLP theory, still unmeasured in
//    isolation — should appear in top-5 now that agg shrinks).
// CSR build unchanged: one packed 64-bit atomic per edge
//   bits [40:63] = incoming-edge count, bits [0:39] = fixed-point wsum (2^-24)
// atomic return value -> edge rank -> atomic-free CSR fill of int2{src,norm}.
// ---------------------------------------------------------------------------

#define WFIX_SCALE 16777216.0f  // 2^24
#define WFIX_MASK  0xFFFFFFFFFFULL

struct alignas(16) H8 { __half2 h[4]; };   // 8 halves = 16 B
struct alignas(8)  H4 { __half2 lo, hi; }; // 4 halves = 8 B

// --- dtype detect: flag=1 if edge_index is int64 (all sampled high words 0) ---
__global__ __launch_bounds__(256) void k_detect(const int* __restrict__ ei,
                                                int* __restrict__ flagp, int E) {
  __shared__ int sm[256];
  int t = threadIdx.x;
  int v = 0;
#pragma unroll
  for (int j = 0; j < 8; ++j) {
    int e = t * 8 + j;           // e < 2048, safely inside both layouts
    if (2 * e + 1 < 2 * E) v |= ei[2 * e + 1];
  }
  sm[t] = v;
  __syncthreads();
  for (int off = 128; off > 0; off >>= 1) {
    if (t < off) sm[t] |= sm[t + off];
    __syncthreads();
  }
  if (t == 0) flagp[0] = (sm[0] == 0) ? 1 : 0;
}

__global__ __launch_bounds__(256) void k_init(unsigned long long* __restrict__ packed,
                                              int N) {
  int i = blockIdx.x * 256 + threadIdx.x;
  if (i < N) packed[i] = 0ULL;
}

// one packed 64-bit atomic per edge; returned old value -> rank within dst row
__global__ __launch_bounds__(256) void k_hist2(const int* __restrict__ ei,
                                               const float* __restrict__ ew,
                                               unsigned long long* __restrict__ packed,
                                               unsigned short* __restrict__ rank,
                                               int E, const int* __restrict__ flagp) {
  int e = blockIdx.x * 256 + threadIdx.x;
  if (e >= E) return;
  int is64 = flagp[0];
  int d = is64 ? ei[2 * E + 2 * e] : ei[E + e];
  unsigned long long wfix = (unsigned long long)(ew[e] * WFIX_SCALE + 0.5f);
  unsigned long long old = atomicAdd(&packed[d], wfix | (1ULL << 40));
  rank[e] = (unsigned short)(old >> 40);
}

// unpack: dinv = rsqrt(1 + wsum), cnt; and block-sum cnt for the scan
__global__ __launch_bounds__(256) void k_dinv_scan1(
    const unsigned long long* __restrict__ packed, float* __restrict__ dinv,
    int* __restrict__ cnt, int* __restrict__ bsum, int N) {
  __shared__ int sm[256];
  int t = threadIdx.x;
  int i = blockIdx.x * 256 + t;
  int c = 0;
  if (i < N) {
    unsigned long long p = packed[i];
    c = (int)(p >> 40);
    float deg = 1.0f + (float)(p & WFIX_MASK) * (1.0f / WFIX_SCALE);
    dinv[i] = rsqrtf(deg);
    cnt[i] = c;
  }
  sm[t] = c;
  __syncthreads();
  for (int off = 128; off > 0; off >>= 1) {
    if (t < off) sm[t] += sm[t + off];
    __syncthreads();
  }
  if (t == 0) bsum[blockIdx.x] = sm[0];
}

__global__ __launch_bounds__(256) void k_scan2(int* __restrict__ bsum,
                                               int* __restrict__ row_start,
                                               int NB, int N, int E) {
  __shared__ int sm[256];
  int t = threadIdx.x;
  int v = (t < NB) ? bsum[t] : 0;
  sm[t] = v;
  __syncthreads();
  for (int off = 1; off < 256; off <<= 1) {
    int add = (t >= off) ? sm[t - off] : 0;
    __syncthreads();
    sm[t] += add;
    __syncthreads();
  }
  if (t < NB) bsum[t] = sm[t] - v;  // exclusive block offsets
  if (t == 0) row_start[N] = E;
}

__global__ __launch_bounds__(256) void k_scan3(const int* __restrict__ cnt,
                                               const int* __restrict__ bsum,
                                               int* __restrict__ row_start, int N) {
  __shared__ int sm[256];
  int t = threadIdx.x;
  int i = blockIdx.x * 256 + t;
  int v = (i < N) ? cnt[i] : 0;
  sm[t] = v;
  __syncthreads();
  for (int off = 1; off < 256; off <<= 1) {
    int add = (t >= off) ? sm[t - off] : 0;
    __syncthreads();
    sm[t] += add;
    __syncthreads();
  }
  if (i < N) row_start[i] = sm[t] - v + bsum[blockIdx.x];
}

// CSR fill, atomic-free: pos = row_start[dst] + rank[e]; one packed int2 store
__global__ __launch_bounds__(256) void k_fill2(const int* __restrict__ ei,
                                               const float* __restrict__ ew,
                                               const float* __restrict__ dinv,
                                               const int* __restrict__ row_start,
                                               const unsigned short* __restrict__ rank,
                                               int2* __restrict__ csr, int E,
                                               const int* __restrict__ flagp) {
  int e = blockIdx.x * 256 + threadIdx.x;
  if (e >= E) return;
  int is64 = flagp[0];
  int s, d;
  if (is64) { s = ei[2 * e]; d = ei[2 * E + 2 * e]; }
  else      { s = ei[e];     d = ei[E + e]; }
  float nw = dinv[s] * ew[e] * dinv[d];
  int pos = row_start[d] + (int)rank[e];
  csr[pos] = make_int2(s, __float_as_int(nw));
}

// --- fp32 register-tiled GEMM: Y[M,NC] = X[M,128] @ W[128,NC], fp16 output ---
// 32 rows per block for TLP (1563 blocks, ~6 blocks/CU).
template <int NC>
__global__ __launch_bounds__(256) void gemm_kernel(const float* __restrict__ X,
                                                   const float* __restrict__ W,
                                                   __half* __restrict__ Y, int M) {
  constexpr int K = 128;
  constexpr int CG = NC / 4;    // col groups: 32 (NC=128) or 16 (NC=64)
  constexpr int RS = 256 / CG;  // row subs: 8 or 16
  constexpr int RI = 32 / RS;   // rows per thread: 4 or 2
  int t = threadIdx.x;
  int cg = t % CG;
  int rs = t / CG;
  int rbase = blockIdx.x * 32;

  float4 acc[RI];
#pragma unroll
  for (int i = 0; i < RI; ++i) acc[i] = make_float4(0.f, 0.f, 0.f, 0.f);

  int rows[RI];
#pragma unroll
  for (int i = 0; i < RI; ++i) {
    int r = rbase + rs + RS * i;
    rows[i] = (r < M) ? r : (M - 1);  // clamp loads, guard stores
  }

  for (int k0 = 0; k0 < K; k0 += 4) {
    float4 w[4];
#pragma unroll
    for (int j = 0; j < 4; ++j)
      w[j] = *(const float4*)&W[(k0 + j) * NC + 4 * cg];
#pragma unroll
    for (int i = 0; i < RI; ++i) {
      float4 xq = *(const float4*)&X[(size_t)rows[i] * K + k0];
      acc[i].x += xq.x * w[0].x + xq.y * w[1].x + xq.z * w[2].x + xq.w * w[3].x;
      acc[i].y += xq.x * w[0].y + xq.y * w[1].y + xq.z * w[2].y + xq.w * w[3].y;
      acc[i].z += xq.x * w[0].z + xq.y * w[1].z + xq.z * w[2].z + xq.w * w[3].z;
      acc[i].w += xq.x * w[0].w + xq.y * w[1].w + xq.z * w[2].w + xq.w * w[3].w;
    }
  }

#pragma unroll
  for (int i = 0; i < RI; ++i) {
    int r = rbase + rs + RS * i;
    if (r < M) {
      H4 v;
      v.lo = __floats2half2_rn(acc[i].x, acc[i].y);
      v.hi = __floats2half2_rn(acc[i].z, acc[i].w);
      *(H4*)&Y[(size_t)r * NC + 4 * cg] = v;
    }
  }
}

__device__ inline void h8_to_f(const H8& g, float* f) {
  float2 t0 = __half22float2(g.h[0]);
  float2 t1 = __half22float2(g.h[1]);
  float2 t2 = __half22float2(g.h[2]);
  float2 t3 = __half22float2(g.h[3]);
  f[0] = t0.x; f[1] = t0.y; f[2] = t1.x; f[3] = t1.y;
  f[4] = t2.x; f[5] = t2.y; f[6] = t3.x; f[7] = t3.y;
}

// --- gather aggregation over fp16 H (atomic-free), fused self+bias(+ReLU) ---
// Lane owns 8 features (16 B). LPN = NC/8 lanes per node. 4-way unrolled
// edge loop: 4 independent csr reads + 4 independent 16 B gathers in flight.
template <int NC, bool RELU>
__global__ __launch_bounds__(256) void agg_half(const __half* __restrict__ H,
                                                const int* __restrict__ row_start,
                                                const int2* __restrict__ csr,
                                                const float* __restrict__ dinv,
                                                const float* __restrict__ bias,
                                                float* __restrict__ OUT, int N) {
  constexpr int LPN = NC / 8;     // 16 or 8
  constexpr int NPB = 256 / LPN;  // 16 or 32
  int t = threadIdx.x;
  int lane = t % LPN;
  int n = blockIdx.x * NPB + t / LPN;
  if (n >= N) return;

  int fbase = lane * 8;
  const __half* Hf = H + fbase;

  int j0 = row_start[n];
  int j1 = row_start[n + 1];
  float acc[8];
#pragma unroll
  for (int k = 0; k < 8; ++k) acc[k] = 0.f;

  int j = j0;
  for (; j + 4 <= j1; j += 4) {
    int2 e0 = csr[j];
    int2 e1 = csr[j + 1];
    int2 e2 = csr[j + 2];
    int2 e3 = csr[j + 3];
    H8 g0 = *(const H8*)&Hf[(size_t)e0.x * NC];
    H8 g1 = *(const H8*)&Hf[(size_t)e1.x * NC];
    H8 g2 = *(const H8*)&Hf[(size_t)e2.x * NC];
    H8 g3 = *(const H8*)&Hf[(size_t)e3.x * NC];
    float w0 = __int_as_float(e0.y);
    float w1 = __int_as_float(e1.y);
    float w2 = __int_as_float(e2.y);
    float w3 = __int_as_float(e3.y);
    float f0[8], f1[8], f2[8], f3[8];
    h8_to_f(g0, f0); h8_to_f(g1, f1); h8_to_f(g2, f2); h8_to_f(g3, f3);
#pragma unroll
    for (int k = 0; k < 8; ++k)
      acc[k] += w0 * f0[k] + w1 * f1[k] + w2 * f2[k] + w3 * f3[k];
  }
  for (; j < j1; ++j) {
    int2 sn = csr[j];
    float w = __int_as_float(sn.y);
    H8 g = *(const H8*)&Hf[(size_t)sn.x * NC];
    float f[8];
    h8_to_f(g, f);
#pragma unroll
    for (int k = 0; k < 8; ++k) acc[k] += w * f[k];
  }

  float di = dinv[n];
  float sw = di * di;
  H8 gs = *(const H8*)&Hf[(size_t)n * NC];
  float fs[8];
  h8_to_f(gs, fs);
  float4 b0 = *(const float4*)&bias[fbase];
  float4 b1 = *(const float4*)&bias[fbase + 4];
  float o[8];
  o[0] = acc[0] + sw * fs[0] + b0.x;
  o[1] = acc[1] + sw * fs[1] + b0.y;
  o[2] = acc[2] + sw * fs[2] + b0.z;
  o[3] = acc[3] + sw * fs[3] + b0.w;
  o[4] = acc[4] + sw * fs[4] + b1.x;
  o[5] = acc[5] + sw * fs[5] + b1.y;
  o[6] = acc[6] + sw * fs[6] + b1.z;
  o[7] = acc[7] + sw * fs[7] + b1.w;
  if (RELU) {
#pragma unroll
    for (int k = 0; k < 8; ++k) o[k] = fmaxf(o[k], 0.f);
  }
  float* op = &OUT[(size_t)n * NC + fbase];
  *(float4*)op       = make_float4(o[0], o[1], o[2], o[3]);
  *(float4*)(op + 4) = make_float4(o[4], o[5], o[6], o[7]);
}

extern "C" void kernel_launch(void* const* d_in, const int* in_sizes, int n_in,
                              void* d_out, int out_size, void* d_ws, size_t ws_size,
                              hipStream_t stream) {
  const float* x  = (const float*)d_in[0];
  const int*   ei = (const int*)d_in[1];
  const float* ew = (const float*)d_in[2];
  const float* W1 = (const float*)d_in[3];
  const float* b1 = (const float*)d_in[4];
  const float* W2 = (const float*)d_in[5];
  const float* b2 = (const float*)d_in[6];
  float* out = (float*)d_out;

  const int IN_D = 128, HID = 128, OUT_D = 64;
  const int N = in_sizes[0] / IN_D;   // 50000
  const int E = in_sizes[2];          // 800000

  char* ws = (char*)d_ws;
  size_t off = 0;
  auto take = [&](size_t bytes) -> void* {
    void* p = ws + off;
    off += (bytes + 255) & ~(size_t)255;
    return p;
  };
  unsigned long long* packed = (unsigned long long*)take((size_t)N * 8);
  float* dinv      = (float*)take((size_t)N * 4);
  int*   cnt       = (int*)take((size_t)N * 4);
  int*   row_start = (int*)take((size_t)(N + 1) * 4);
  int*   bsum      = (int*)take(256 * 4);
  int*   flag      = (int*)take(256);
  unsigned short* rank = (unsigned short*)take((size_t)E * 2);
  int2*  csr       = (int2*)take((size_t)E * 8);
  __half* h1       = (__half*)take((size_t)N * HID * 2);   // fp16 agg input
  float*  h2       = (float*)take((size_t)N * HID * 4);    // fp32 gemm2 input
  __half* h3       = (__half*)take((size_t)N * OUT_D * 2); // fp16 agg input

  int nb_n = (N + 255) / 256;  // 196
  int nb_e = (E + 255) / 256;  // 3125
  int nb_g = (N + 31) / 32;    // 1563

  hipLaunchKernelGGL(k_detect, dim3(1), dim3(256), 0, stream, ei, flag, E);
  hipLaunchKernelGGL(k_init, dim3(nb_n), dim3(256), 0, stream, packed, N);
  hipLaunchKernelGGL(k_hist2, dim3(nb_e), dim3(256), 0, stream, ei, ew, packed, rank, E, flag);
  hipLaunchKernelGGL(k_dinv_scan1, dim3(nb_n), dim3(256), 0, stream, packed, dinv, cnt, bsum, N);
  hipLaunchKernelGGL(k_scan2, dim3(1), dim3(256), 0, stream, bsum, row_start, nb_n, N, E);
  hipLaunchKernelGGL(k_scan3, dim3(nb_n), dim3(256), 0, stream, cnt, bsum, row_start, N);
  hipLaunchKernelGGL(k_fill2, dim3(nb_e), dim3(256), 0, stream, ei, ew, dinv, row_start,
                     rank, csr, E, flag);
  hipLaunchKernelGGL((gemm_kernel<128>), dim3(nb_g), dim3(256), 0, stream, x, W1, h1, N);
  hipLaunchKernelGGL((agg_half<128, true>), dim3((N + 15) / 16), dim3(256), 0, stream,
                     h1, row_start, csr, dinv, b1, h2, N);
  hipLaunchKernelGGL((gemm_kernel<64>), dim3(nb_g), dim3(256), 0, stream, h2, W2, h3, N);
  hipLaunchKernelGGL((agg_half<64, false>), dim3((N + 31) / 32), dim3(256), 0, stream,
                     h3, row_start, csr, dinv, b2, out, N);
}

// Round 16
// 223.509 us; speedup vs baseline: 1.7523x; 1.3269x over previous
//
#include <hip/hip_runtime.h>
#include <hip/hip_fp16.h>
#include <math.h>

// ---------------------------------------------------------------------------
// GCN 2-layer forward on MI355X.
// Round 15 resubmit (bench never ran — GPU acquisition timeout): MFMA GEMM.
// Round-14 falsified the TLP theory (occupancy 22->45%, dur 62->66 us,
// VALUBusy pinned ~24%): the fp32 vector pipe at 25 TF is the engine limit.
// Since fp16 feature precision already passed (absmax 2^-8), cast GEMM inputs
// to fp16 and use v_mfma_f32_16x16x32_f16 (fp32 accum):
//   * k_cvt_half: X -> fp16 once.  k_packW: W1/W2 -> fragment-ordered fp16.
//   * gemm_mfma: 64-row blocks, 4 waves x 16-row strips; packed W staged in
//     LDS (32/16 KB); A-frags read 16 B/lane direct from global (X read once).
//     Fragment maps (gfx950, HW-verified C/D m89): A row=l&15 k=(l>>4)*8+j;
//     B col=l&15 same k; C/D col=l&15 row=(l>>4)*4+reg.
//   * agg_half now emits fp16 h2 directly (gemm2 consumes fp16).
// CSR build unchanged: one packed 64-bit atomic per edge; rank -> atomic-free
// fill. agg: unsliced 4-way-unrolled fp16 gather (round-14 validated).
// ---------------------------------------------------------------------------

#define WFIX_SCALE 16777216.0f  // 2^24
#define WFIX_MASK  0xFFFFFFFFFFULL

typedef _Float16 half8 __attribute__((ext_vector_type(8)));
typedef float f32x4 __attribute__((ext_vector_type(4)));

struct alignas(16) H8 { __half2 h[4]; };   // 8 halves = 16 B

// --- dtype detect: flag=1 if edge_index is int64 (all sampled high words 0) ---
__global__ __launch_bounds__(256) void k_detect(const int* __restrict__ ei,
                                                int* __restrict__ flagp, int E) {
  __shared__ int sm[256];
  int t = threadIdx.x;
  int v = 0;
#pragma unroll
  for (int j = 0; j < 8; ++j) {
    int e = t * 8 + j;
    if (2 * e + 1 < 2 * E) v |= ei[2 * e + 1];
  }
  sm[t] = v;
  __syncthreads();
  for (int off = 128; off > 0; off >>= 1) {
    if (t < off) sm[t] |= sm[t + off];
    __syncthreads();
  }
  if (t == 0) flagp[0] = (sm[0] == 0) ? 1 : 0;
}

__global__ __launch_bounds__(256) void k_init(unsigned long long* __restrict__ packed,
                                              int N) {
  int i = blockIdx.x * 256 + threadIdx.x;
  if (i < N) packed[i] = 0ULL;
}

__global__ __launch_bounds__(256) void k_hist2(const int* __restrict__ ei,
                                               const float* __restrict__ ew,
                                               unsigned long long* __restrict__ packed,
                                               unsigned short* __restrict__ rank,
                                               int E, const int* __restrict__ flagp) {
  int e = blockIdx.x * 256 + threadIdx.x;
  if (e >= E) return;
  int is64 = flagp[0];
  int d = is64 ? ei[2 * E + 2 * e] : ei[E + e];
  unsigned long long wfix = (unsigned long long)(ew[e] * WFIX_SCALE + 0.5f);
  unsigned long long old = atomicAdd(&packed[d], wfix | (1ULL << 40));
  rank[e] = (unsigned short)(old >> 40);
}

__global__ __launch_bounds__(256) void k_dinv_scan1(
    const unsigned long long* __restrict__ packed, float* __restrict__ dinv,
    int* __restrict__ cnt, int* __restrict__ bsum, int N) {
  __shared__ int sm[256];
  int t = threadIdx.x;
  int i = blockIdx.x * 256 + t;
  int c = 0;
  if (i < N) {
    unsigned long long p = packed[i];
    c = (int)(p >> 40);
    float deg = 1.0f + (float)(p & WFIX_MASK) * (1.0f / WFIX_SCALE);
    dinv[i] = rsqrtf(deg);
    cnt[i] = c;
  }
  sm[t] = c;
  __syncthreads();
  for (int off = 128; off > 0; off >>= 1) {
    if (t < off) sm[t] += sm[t + off];
    __syncthreads();
  }
  if (t == 0) bsum[blockIdx.x] = sm[0];
}

__global__ __launch_bounds__(256) void k_scan2(int* __restrict__ bsum,
                                               int* __restrict__ row_start,
                                               int NB, int N, int E) {
  __shared__ int sm[256];
  int t = threadIdx.x;
  int v = (t < NB) ? bsum[t] : 0;
  sm[t] = v;
  __syncthreads();
  for (int off = 1; off < 256; off <<= 1) {
    int add = (t >= off) ? sm[t - off] : 0;
    __syncthreads();
    sm[t] += add;
    __syncthreads();
  }
  if (t < NB) bsum[t] = sm[t] - v;
  if (t == 0) row_start[N] = E;
}

__global__ __launch_bounds__(256) void k_scan3(const int* __restrict__ cnt,
                                               const int* __restrict__ bsum,
                                               int* __restrict__ row_start, int N) {
  __shared__ int sm[256];
  int t = threadIdx.x;
  int i = blockIdx.x * 256 + t;
  int v = (i < N) ? cnt[i] : 0;
  sm[t] = v;
  __syncthreads();
  for (int off = 1; off < 256; off <<= 1) {
    int add = (t >= off) ? sm[t - off] : 0;
    __syncthreads();
    sm[t] += add;
    __syncthreads();
  }
  if (i < N) row_start[i] = sm[t] - v + bsum[blockIdx.x];
}

__global__ __launch_bounds__(256) void k_fill2(const int* __restrict__ ei,
                                               const float* __restrict__ ew,
                                               const float* __restrict__ dinv,
                                               const int* __restrict__ row_start,
                                               const unsigned short* __restrict__ rank,
                                               int2* __restrict__ csr, int E,
                                               const int* __restrict__ flagp) {
  int e = blockIdx.x * 256 + threadIdx.x;
  if (e >= E) return;
  int is64 = flagp[0];
  int s, d;
  if (is64) { s = ei[2 * e]; d = ei[2 * E + 2 * e]; }
  else      { s = ei[e];     d = ei[E + e]; }
  float nw = dinv[s] * ew[e] * dinv[d];
  int pos = row_start[d] + (int)rank[e];
  csr[pos] = make_int2(s, __float_as_int(nw));
}

// --- fp32 -> fp16 convert (X), 8 elems/thread; n must be /8 (6.4M is) ---
__global__ __launch_bounds__(256) void k_cvt_half(const float* __restrict__ src,
                                                  _Float16* __restrict__ dst, int n) {
  int i = blockIdx.x * 256 + threadIdx.x;
  int base = i * 8;
  if (base + 8 <= n) {
    float4 a = *(const float4*)(src + base);
    float4 b = *(const float4*)(src + base + 4);
    half8 h = {(_Float16)a.x, (_Float16)a.y, (_Float16)a.z, (_Float16)a.w,
               (_Float16)b.x, (_Float16)b.y, (_Float16)b.z, (_Float16)b.w};
    *(half8*)(dst + base) = h;
  } else {
    for (int k = base; k < n; ++k) dst[k] = (_Float16)src[k];
  }
}

// --- pack W[K=128][NC] into MFMA B-fragment order: [kt][nt][lane][8] fp16 ---
// B-frag for v_mfma_f32_16x16x32_f16: lane l supplies B[(l>>4)*8+j][l&15].
__global__ __launch_bounds__(256) void k_packW(const float* __restrict__ W,
                                               _Float16* __restrict__ Wp,
                                               int NT, int total) {
  int idx = blockIdx.x * 256 + threadIdx.x;
  if (idx >= total) return;
  int j  = idx & 7;
  int l  = (idx >> 3) & 63;
  int nt = (idx >> 9) % NT;
  int kt = (idx >> 9) / NT;
  int krow = kt * 32 + (l >> 4) * 8 + j;
  int col  = nt * 16 + (l & 15);
  Wp[idx] = (_Float16)W[krow * (NT * 16) + col];
}

// --- MFMA GEMM: Y[M, NT*16] = Xh[M,128] @ W (packed), fp16 in / fp32 acc ---
// 64 rows/block, 4 waves x 16-row strips, NT output tiles per wave.
template <int NT>
__global__ __launch_bounds__(256) void gemm_mfma(const _Float16* __restrict__ Xh,
                                                 const _Float16* __restrict__ Wp,
                                                 _Float16* __restrict__ Y, int M) {
  constexpr int NC = NT * 16;
  constexpr int CH = 4 * NT * 64;          // 16-byte chunks of packed W
  __shared__ ulonglong2 wlraw[CH];         // 32 KB (NT=8) / 16 KB (NT=4)
  _Float16* wl = (_Float16*)wlraw;

  int t = threadIdx.x;
  for (int c = t; c < CH; c += 256)
    wlraw[c] = ((const ulonglong2*)Wp)[c];
  __syncthreads();

  int w = t >> 6;          // wave 0..3
  int l = t & 63;
  int r16 = l & 15;
  int kq  = l >> 4;        // 0..3
  int rowA = blockIdx.x * 64 + w * 16 + r16;
  if (rowA >= M) rowA = M - 1;             // clamp loads; stores guarded

  f32x4 acc[NT];
#pragma unroll
  for (int i = 0; i < NT; ++i) acc[i] = (f32x4){0.f, 0.f, 0.f, 0.f};

  const _Float16* xrow = Xh + (size_t)rowA * 128 + kq * 8;
#pragma unroll
  for (int kt = 0; kt < 4; ++kt) {
    half8 a = *(const half8*)(xrow + kt * 32);
    const _Float16* wbase = wl + ((size_t)(kt * NT) * 64 + l) * 8;
#pragma unroll
    for (int nt = 0; nt < NT; ++nt) {
      half8 b = *(const half8*)(wbase + (size_t)nt * 64 * 8);
      acc[nt] = __builtin_amdgcn_mfma_f32_16x16x32_f16(a, b, acc[nt], 0, 0, 0);
    }
  }

  // C/D: col = l&15, row = (l>>4)*4 + reg  [HW-verified m89]
  int orow0 = blockIdx.x * 64 + w * 16 + kq * 4;
#pragma unroll
  for (int nt = 0; nt < NT; ++nt) {
#pragma unroll
    for (int r = 0; r < 4; ++r) {
      int gr = orow0 + r;
      if (gr < M) Y[(size_t)gr * NC + nt * 16 + r16] = (_Float16)acc[nt][r];
    }
  }
}

__device__ inline void h8_to_f(const H8& g, float* f) {
  float2 t0 = __half22float2(g.h[0]);
  float2 t1 = __half22float2(g.h[1]);
  float2 t2 = __half22float2(g.h[2]);
  float2 t3 = __half22float2(g.h[3]);
  f[0] = t0.x; f[1] = t0.y; f[2] = t1.x; f[3] = t1.y;
  f[4] = t2.x; f[5] = t2.y; f[6] = t3.x; f[7] = t3.y;
}

// --- gather aggregation over fp16 H, fused self+bias(+ReLU); OutT fp16/fp32 ---
template <int NC, bool RELU, typename OutT>
__global__ __launch_bounds__(256) void agg_half(const __half* __restrict__ H,
                                                const int* __restrict__ row_start,
                                                const int2* __restrict__ csr,
                                                const float* __restrict__ dinv,
                                                const float* __restrict__ bias,
                                                OutT* __restrict__ OUT, int N) {
  constexpr int LPN = NC / 8;     // 16 or 8
  constexpr int NPB = 256 / LPN;  // 16 or 32
  int t = threadIdx.x;
  int lane = t % LPN;
  int n = blockIdx.x * NPB + t / LPN;
  if (n >= N) return;

  int fbase = lane * 8;
  const __half* Hf = H + fbase;

  int j0 = row_start[n];
  int j1 = row_start[n + 1];
  float acc[8];
#pragma unroll
  for (int k = 0; k < 8; ++k) acc[k] = 0.f;

  int j = j0;
  for (; j + 4 <= j1; j += 4) {
    int2 e0 = csr[j];
    int2 e1 = csr[j + 1];
    int2 e2 = csr[j + 2];
    int2 e3 = csr[j + 3];
    H8 g0 = *(const H8*)&Hf[(size_t)e0.x * NC];
    H8 g1 = *(const H8*)&Hf[(size_t)e1.x * NC];
    H8 g2 = *(const H8*)&Hf[(size_t)e2.x * NC];
    H8 g3 = *(const H8*)&Hf[(size_t)e3.x * NC];
    float w0 = __int_as_float(e0.y);
    float w1 = __int_as_float(e1.y);
    float w2 = __int_as_float(e2.y);
    float w3 = __int_as_float(e3.y);
    float f0[8], f1[8], f2[8], f3[8];
    h8_to_f(g0, f0); h8_to_f(g1, f1); h8_to_f(g2, f2); h8_to_f(g3, f3);
#pragma unroll
    for (int k = 0; k < 8; ++k)
      acc[k] += w0 * f0[k] + w1 * f1[k] + w2 * f2[k] + w3 * f3[k];
  }
  for (; j < j1; ++j) {
    int2 sn = csr[j];
    float w = __int_as_float(sn.y);
    H8 g = *(const H8*)&Hf[(size_t)sn.x * NC];
    float f[8];
    h8_to_f(g, f);
#pragma unroll
    for (int k = 0; k < 8; ++k) acc[k] += w * f[k];
  }

  float di = dinv[n];
  float sw = di * di;
  H8 gs = *(const H8*)&Hf[(size_t)n * NC];
  float fs[8];
  h8_to_f(gs, fs);
  float4 b0 = *(const float4*)&bias[fbase];
  float4 b1 = *(const float4*)&bias[fbase + 4];
  float o[8];
  o[0] = acc[0] + sw * fs[0] + b0.x;
  o[1] = acc[1] + sw * fs[1] + b0.y;
  o[2] = acc[2] + sw * fs[2] + b0.z;
  o[3] = acc[3] + sw * fs[3] + b0.w;
  o[4] = acc[4] + sw * fs[4] + b1.x;
  o[5] = acc[5] + sw * fs[5] + b1.y;
  o[6] = acc[6] + sw * fs[6] + b1.z;
  o[7] = acc[7] + sw * fs[7] + b1.w;
  if (RELU) {
#pragma unroll
    for (int k = 0; k < 8; ++k) o[k] = fmaxf(o[k], 0.f);
  }
  if constexpr (sizeof(OutT) == 2) {
    H8 hv;
    hv.h[0] = __floats2half2_rn(o[0], o[1]);
    hv.h[1] = __floats2half2_rn(o[2], o[3]);
    hv.h[2] = __floats2half2_rn(o[4], o[5]);
    hv.h[3] = __floats2half2_rn(o[6], o[7]);
    *(H8*)&OUT[(size_t)n * NC + fbase] = hv;
  } else {
    float* op = (float*)&OUT[(size_t)n * NC + fbase];
    *(float4*)op       = make_float4(o[0], o[1], o[2], o[3]);
    *(float4*)(op + 4) = make_float4(o[4], o[5], o[6], o[7]);
  }
}

extern "C" void kernel_launch(void* const* d_in, const int* in_sizes, int n_in,
                              void* d_out, int out_size, void* d_ws, size_t ws_size,
                              hipStream_t stream) {
  const float* x  = (const float*)d_in[0];
  const int*   ei = (const int*)d_in[1];
  const float* ew = (const float*)d_in[2];
  const float* W1 = (const float*)d_in[3];
  const float* b1 = (const float*)d_in[4];
  const float* W2 = (const float*)d_in[5];
  const float* b2 = (const float*)d_in[6];
  float* out = (float*)d_out;

  const int IN_D = 128, HID = 128, OUT_D = 64;
  const int N = in_sizes[0] / IN_D;   // 50000
  const int E = in_sizes[2];          // 800000

  char* ws = (char*)d_ws;
  size_t off = 0;
  auto take = [&](size_t bytes) -> void* {
    void* p = ws + off;
    off += (bytes + 255) & ~(size_t)255;
    return p;
  };
  unsigned long long* packed = (unsigned long long*)take((size_t)N * 8);
  float* dinv      = (float*)take((size_t)N * 4);
  int*   cnt       = (int*)take((size_t)N * 4);
  int*   row_start = (int*)take((size_t)(N + 1) * 4);
  int*   bsum      = (int*)take(256 * 4);
  int*   flag      = (int*)take(256);
  unsigned short* rank = (unsigned short*)take((size_t)E * 2);
  int2*  csr       = (int2*)take((size_t)E * 8);
  _Float16* Xh     = (_Float16*)take((size_t)N * IN_D * 2);
  _Float16* W1p    = (_Float16*)take((size_t)16384 * 2);
  _Float16* W2p    = (_Float16*)take((size_t)8192 * 2);
  _Float16* h1     = (_Float16*)take((size_t)N * HID * 2);
  _Float16* h2     = (_Float16*)take((size_t)N * HID * 2);
  _Float16* h3     = (_Float16*)take((size_t)N * OUT_D * 2);

  int nb_n = (N + 255) / 256;        // 196
  int nb_e = (E + 255) / 256;        // 3125
  int nb_g = (N + 63) / 64;          // 782
  int nb_x = (N * IN_D / 8 + 255) / 256;  // 3125

  hipLaunchKernelGGL(k_detect, dim3(1), dim3(256), 0, stream, ei, flag, E);
  hipLaunchKernelGGL(k_init, dim3(nb_n), dim3(256), 0, stream, packed, N);
  hipLaunchKernelGGL(k_hist2, dim3(nb_e), dim3(256), 0, stream, ei, ew, packed, rank, E, flag);
  hipLaunchKernelGGL(k_dinv_scan1, dim3(nb_n), dim3(256), 0, stream, packed, dinv, cnt, bsum, N);
  hipLaunchKernelGGL(k_scan2, dim3(1), dim3(256), 0, stream, bsum, row_start, nb_n, N, E);
  hipLaunchKernelGGL(k_scan3, dim3(nb_n), dim3(256), 0, stream, cnt, bsum, row_start, N);
  hipLaunchKernelGGL(k_fill2, dim3(nb_e), dim3(256), 0, stream, ei, ew, dinv, row_start,
                     rank, csr, E, flag);
  hipLaunchKernelGGL(k_cvt_half, dim3(nb_x), dim3(256), 0, stream, x, Xh, N * IN_D);
  hipLaunchKernelGGL(k_packW, dim3(64), dim3(256), 0, stream, W1, W1p, 8, 16384);
  hipLaunchKernelGGL(k_packW, dim3(32), dim3(256), 0, stream, W2, W2p, 4, 8192);

  hipLaunchKernelGGL((gemm_mfma<8>), dim3(nb_g), dim3(256), 0, stream, Xh, W1p, h1, N);
  hipLaunchKernelGGL((agg_half<128, true, _Float16>), dim3((N + 15) / 16), dim3(256), 0,
                     stream, (const __half*)h1, row_start, csr, dinv, b1, h2, N);
  hipLaunchKernelGGL((gemm_mfma<4>), dim3(nb_g), dim3(256), 0, stream, h2, W2p, h3, N);
  hipLaunchKernelGGL((agg_half<64, false, float>), dim3((N + 31) / 32), dim3(256), 0,
                     stream, (const __half*)h3, row_start, csr, dinv, b2, out, N);
}